// Round 2
// baseline (181.934 us; speedup 1.0000x reference)
//
#include <hip/hip_runtime.h>

#define R_   1024
#define B_   4
#define C_   256
#define H_   64
#define W_   64
#define PHW_ 49

__device__ __forceinline__ void cell_w(float start, float end, float s, float& g0, float& g1) {
    float y0 = fmaxf(start, s);
    float yl = fmaxf(fminf(end, s + 1.0f), y0);
    float a  = y0 - s;
    float la = yl - s;
    g0 = la - 0.5f * la * la - a + 0.5f * a * a;
    g1 = 0.5f * la * la - 0.5f * a * a;
}

// Compute per-bin geometry + separable node weights.
// WY[dy] = g0(cell dy) + g1(cell dy-1)  (integral of hat basis at node h0+dy).
__device__ __forceinline__ bool bin_geom(const float* __restrict__ rois, int r, int ph, int pw,
                                         int& bb, int& h0, int& w0, int& npy, int& npx,
                                         float wy[7], float wx[7], float& invwin) {
    const float* roi = rois + r * 5;
    bb = (int)roi[0];
    float x1 = roi[1] * 0.0625f, y1 = roi[2] * 0.0625f;
    float x2 = roi[3] * 0.0625f, y2 = roi[4] * 0.0625f;
    float rw = fmaxf(x2 - x1, 0.0f), rh = fmaxf(y2 - y1, 0.0f);
    float bw = rw / 7.0f, bh = rh / 7.0f;
    float win = bw * bh;
    if (!(win > 0.0f)) return false;
    float ws = x1 + bw * (float)pw, we = ws + bw;
    float hs = y1 + bh * (float)ph, he = hs + bh;
    float s0w = floorf(ws), s0h = floorf(hs);
    w0 = (int)s0w; h0 = (int)s0h;
#pragma unroll
    for (int i = 0; i < 7; ++i) { wy[i] = 0.0f; wx[i] = 0.0f; }
#pragma unroll
    for (int o = 0; o < 6; ++o) {
        float g0, g1;
        cell_w(hs, he, s0h + (float)o, g0, g1);
        wy[o] += g0; wy[o + 1] += g1;
        cell_w(ws, we, s0w + (float)o, g0, g1);
        wx[o] += g0; wx[o + 1] += g1;
    }
    // node dy has weight > 0 iff dy < (end - floor(start)) + 1
    npy = min(7, max(0, (int)ceilf(he - s0h + 1.0f)));
    npx = min(7, max(0, (int)ceilf(we - s0w + 1.0f)));
    invwin = 1.0f / win;
    return true;
}

// ---------------- transpose (B,C,H,W) -> (B,H*W,C) ----------------
__global__ __launch_bounds__(256) void transpose_bchw_bhwc(const float* __restrict__ in,
                                                           float* __restrict__ out) {
    __shared__ float tile[32][33];
    int b  = blockIdx.z;
    int c0 = blockIdx.y * 32;
    int p0 = blockIdx.x * 32;   // h*w index
    int tx = threadIdx.x;       // 0..31
    int ty = threadIdx.y;       // 0..7
    const float* src = in + (size_t)b * C_ * (H_ * W_);
#pragma unroll
    for (int i = 0; i < 32; i += 8)
        tile[ty + i][tx] = src[(size_t)(c0 + ty + i) * (H_ * W_) + (p0 + tx)];
    __syncthreads();
    float* dst = out + (size_t)b * (H_ * W_) * C_;
#pragma unroll
    for (int i = 0; i < 32; i += 8)
        dst[(size_t)(p0 + ty + i) * C_ + (c0 + tx)] = tile[tx][ty + i];
}

// ---------------- main kernel: channels-last gather ----------------
// 1 wave per bin (r,ph,pw); lane handles 4 channels via float4.
__global__ __launch_bounds__(256) void prroi_pool_t(const float* __restrict__ fT,
                                                    const float* __restrict__ rois,
                                                    float* __restrict__ out) {
    int wid  = threadIdx.x >> 6;
    int lane = threadIdx.x & 63;
    int bin  = blockIdx.x * 4 + wid;   // grid sized exactly: R_*49 % 4 == 0
    int r  = bin / 49;
    int k  = bin - r * 49;
    int ph = k / 7;
    int pw = k - ph * 7;

    int bb, h0, w0, npy, npx;
    float wy[7], wx[7], invwin;
    bool ok = bin_geom(rois, r, ph, pw, bb, h0, w0, npy, npx, wy, wx, invwin);

    int c0 = lane * 4;
    float* op = out + ((size_t)r * C_ + c0) * PHW_ + k;
    if (!ok) {
        op[0] = 0.0f; op[PHW_] = 0.0f; op[2 * PHW_] = 0.0f; op[3 * PHW_] = 0.0f;
        return;
    }

    const float* fb = fT + (size_t)bb * (H_ * W_ * C_) + c0;
    float ax = 0.0f, ay = 0.0f, az = 0.0f, aw = 0.0f;
#pragma unroll
    for (int dy = 0; dy < 7; ++dy) {
        int hh = h0 + dy;
        if (dy >= npy || hh < 0 || hh >= H_) continue;   // wave-uniform
        const float* rp = fb + (hh * W_ + w0) * C_;
        float rx = 0.0f, ry = 0.0f, rz = 0.0f, rw = 0.0f;
#pragma unroll
        for (int dx = 0; dx < 7; ++dx) {
            int wwp = w0 + dx;
            if (dx >= npx || wwp < 0 || wwp >= W_) continue;   // wave-uniform
            float4 v = *reinterpret_cast<const float4*>(rp + dx * C_);
            float g = wx[dx];
            rx = fmaf(g, v.x, rx);
            ry = fmaf(g, v.y, ry);
            rz = fmaf(g, v.z, rz);
            rw = fmaf(g, v.w, rw);
        }
        float g = wy[dy];
        ax = fmaf(g, rx, ax);
        ay = fmaf(g, ry, ay);
        az = fmaf(g, rz, az);
        aw = fmaf(g, rw, aw);
    }
    op[0]        = ax * invwin;
    op[PHW_]     = ay * invwin;
    op[2 * PHW_] = az * invwin;
    op[3 * PHW_] = aw * invwin;
}

// ---------------- fallback: original (B,C,H,W) layout ----------------
__global__ __launch_bounds__(256) void prroi_pool_direct(const float* __restrict__ f,
                                                         const float* __restrict__ rois,
                                                         float* __restrict__ out) {
    int bin = blockIdx.x;
    int r  = bin / 49;
    int k  = bin - r * 49;
    int ph = k / 7;
    int pw = k - ph * 7;
    int c = threadIdx.x;

    int bb, h0, w0, npy, npx;
    float wy[7], wx[7], invwin;
    bool ok = bin_geom(rois, r, ph, pw, bb, h0, w0, npy, npx, wy, wx, invwin);

    size_t oidx = ((size_t)r * C_ + c) * PHW_ + k;
    if (!ok) { out[oidx] = 0.0f; return; }

    const float* fb = f + ((size_t)bb * C_ + c) * (H_ * W_);
    float acc = 0.0f;
#pragma unroll
    for (int dy = 0; dy < 7; ++dy) {
        int hh = h0 + dy;
        if (dy >= npy || hh < 0 || hh >= H_) continue;
        float row = 0.0f;
#pragma unroll
        for (int dx = 0; dx < 7; ++dx) {
            int wwp = w0 + dx;
            if (dx >= npx || wwp < 0 || wwp >= W_) continue;
            row = fmaf(wx[dx], fb[hh * W_ + wwp], row);
        }
        acc = fmaf(wy[dy], row, acc);
    }
    out[oidx] = acc * invwin;
}

extern "C" void kernel_launch(void* const* d_in, const int* in_sizes, int n_in,
                              void* d_out, int out_size, void* d_ws, size_t ws_size,
                              hipStream_t stream) {
    const float* feat = (const float*)d_in[0];
    const float* rois = (const float*)d_in[1];
    float* out = (float*)d_out;

    const size_t feat_bytes = (size_t)B_ * C_ * H_ * W_ * sizeof(float);
    const int nbins = R_ * PHW_;          // 50176

    if (ws_size >= feat_bytes) {
        float* fT = (float*)d_ws;
        dim3 tb(32, 8, 1);
        dim3 tg((H_ * W_) / 32, C_ / 32, B_);
        transpose_bchw_bhwc<<<tg, tb, 0, stream>>>(feat, fT);
        prroi_pool_t<<<nbins / 4, 256, 0, stream>>>(fT, rois, out);
    } else {
        prroi_pool_direct<<<nbins, 256, 0, stream>>>(feat, rois, out);
    }
}

// Round 3
// 121.458 us; speedup vs baseline: 1.4979x; 1.4979x over previous
//
#include <hip/hip_runtime.h>

#define R_   1024
#define B_   4
#define C_   256
#define H_   64
#define W_   64
#define PHW_ 49
#define LDSP 257   // 49 rows x 257 floats: +1 pad -> conflict-free transposed read

__device__ __forceinline__ void cell_w(float start, float end, float s, float& g0, float& g1) {
    float y0 = fmaxf(start, s);
    float yl = fmaxf(fminf(end, s + 1.0f), y0);
    float a  = y0 - s;
    float la = yl - s;
    g0 = la - 0.5f * la * la - a + 0.5f * a * a;
    g1 = 0.5f * la * la - 0.5f * a * a;
}

__device__ __forceinline__ bool bin_geom(const float* __restrict__ rois, int r, int ph, int pw,
                                         int& bb, int& h0, int& w0, int& npy, int& npx,
                                         float wy[7], float wx[7], float& invwin) {
    const float* roi = rois + r * 5;
    bb = (int)roi[0];
    float x1 = roi[1] * 0.0625f, y1 = roi[2] * 0.0625f;
    float x2 = roi[3] * 0.0625f, y2 = roi[4] * 0.0625f;
    float rw = fmaxf(x2 - x1, 0.0f), rh = fmaxf(y2 - y1, 0.0f);
    float bw = rw / 7.0f, bh = rh / 7.0f;
    float win = bw * bh;
    if (!(win > 0.0f)) return false;
    float ws = x1 + bw * (float)pw, we = ws + bw;
    float hs = y1 + bh * (float)ph, he = hs + bh;
    float s0w = floorf(ws), s0h = floorf(hs);
    w0 = (int)s0w; h0 = (int)s0h;
#pragma unroll
    for (int i = 0; i < 7; ++i) { wy[i] = 0.0f; wx[i] = 0.0f; }
#pragma unroll
    for (int o = 0; o < 6; ++o) {
        float g0, g1;
        cell_w(hs, he, s0h + (float)o, g0, g1);
        wy[o] += g0; wy[o + 1] += g1;
        cell_w(ws, we, s0w + (float)o, g0, g1);
        wx[o] += g0; wx[o + 1] += g1;
    }
    npy = min(7, max(0, (int)ceilf(he - s0h + 1.0f)));
    npx = min(7, max(0, (int)ceilf(we - s0w + 1.0f)));
    invwin = 1.0f / win;
    return true;
}

// ---------------- transpose (B,C,H,W) -> (B,H*W,C) ----------------
__global__ __launch_bounds__(256) void transpose_bchw_bhwc(const float* __restrict__ in,
                                                           float* __restrict__ out) {
    __shared__ float tile[32][33];
    int b  = blockIdx.z;
    int c0 = blockIdx.y * 32;
    int p0 = blockIdx.x * 32;
    int tx = threadIdx.x;
    int ty = threadIdx.y;
    const float* src = in + (size_t)b * C_ * (H_ * W_);
#pragma unroll
    for (int i = 0; i < 32; i += 8)
        tile[ty + i][tx] = src[(size_t)(c0 + ty + i) * (H_ * W_) + (p0 + tx)];
    __syncthreads();
    float* dst = out + (size_t)b * (H_ * W_) * C_;
#pragma unroll
    for (int i = 0; i < 32; i += 8)
        dst[(size_t)(p0 + ty + i) * C_ + (c0 + tx)] = tile[tx][ty + i];
}

// ---------------- deterministic bucket sort of ROIs by (batch, y-band) ----------------
// 1 block x 64 lanes; ballot-based stable counting sort over 16 keys. Fully deterministic.
__global__ __launch_bounds__(64) void make_perm(const float* __restrict__ rois,
                                                int* __restrict__ perm) {
    int lane = threadIdx.x;
    unsigned long long below = (1ull << lane) - 1ull;
    int key[16];
#pragma unroll
    for (int i = 0; i < 16; ++i) {
        int idx = i * 64 + lane;
        const float* roi = rois + idx * 5;
        int b = (int)roi[0];
        float yc = (roi[2] + roi[4]) * 0.5f * 0.0625f;   // feature-space y center (0..~64)
        int yb = min(3, max(0, (int)(yc * 0.0625f)));     // /16 -> 4 bands
        key[i] = b * 4 + yb;
    }
    int cnt[16];
#pragma unroll
    for (int k = 0; k < 16; ++k) cnt[k] = 0;
    for (int i = 0; i < 16; ++i)
#pragma unroll
        for (int k = 0; k < 16; ++k)
            cnt[k] += __popcll(__ballot(key[i] == k));
    int off[16]; int acc = 0;
#pragma unroll
    for (int k = 0; k < 16; ++k) { off[k] = acc; acc += cnt[k]; }
    for (int i = 0; i < 16; ++i) {
#pragma unroll
        for (int k = 0; k < 16; ++k) {
            unsigned long long m = __ballot(key[i] == k);
            if (key[i] == k)
                perm[off[k] + __popcll(m & below)] = i * 64 + lane;
            off[k] += __popcll(m);
        }
    }
}

// ---------------- main: one block per ROI, LDS-staged coalesced output ----------------
__global__ __launch_bounds__(512) void prroi_pool_roi(const float* __restrict__ fT,
                                                      const float* __restrict__ rois,
                                                      const int* __restrict__ perm,
                                                      float* __restrict__ out) {
    __shared__ float lds_out[PHW_ * LDSP];
    int bid  = blockIdx.x;
    // XCD-aware chunking over the sorted order: XCD x gets sorted ROIs [x*128,(x+1)*128)
    int spos = ((bid & 7) << 7) | (bid >> 3);
    int r    = perm[spos];
    int wid  = threadIdx.x >> 6;    // 0..7
    int lane = threadIdx.x & 63;
    int c0   = lane * 4;

    for (int k = wid; k < PHW_; k += 8) {
        int ph = k / 7, pw = k - ph * 7;
        int bb, h0, w0, npy, npx;
        float wy[7], wx[7], invwin;
        bool ok = bin_geom(rois, r, ph, pw, bb, h0, w0, npy, npx, wy, wx, invwin);
        float ax = 0.0f, ay = 0.0f, az = 0.0f, aw = 0.0f;
        if (ok) {
            const float* fb = fT + (size_t)bb * (H_ * W_ * C_) + c0;
#pragma unroll
            for (int dy = 0; dy < 7; ++dy) {
                int hh = h0 + dy;
                if (dy >= npy || hh < 0 || hh >= H_) continue;   // wave-uniform
                const float* rp = fb + (hh * W_ + w0) * C_;
                float rx = 0.0f, ry = 0.0f, rz = 0.0f, rw = 0.0f;
#pragma unroll
                for (int dx = 0; dx < 7; ++dx) {
                    int wwp = w0 + dx;
                    if (dx >= npx || wwp < 0 || wwp >= W_) continue;
                    float4 v = *reinterpret_cast<const float4*>(rp + dx * C_);
                    float g = wx[dx];
                    rx = fmaf(g, v.x, rx);
                    ry = fmaf(g, v.y, ry);
                    rz = fmaf(g, v.z, rz);
                    rw = fmaf(g, v.w, rw);
                }
                float g = wy[dy];
                ax = fmaf(g, rx, ax);
                ay = fmaf(g, ry, ay);
                az = fmaf(g, rz, az);
                aw = fmaf(g, rw, aw);
            }
            ax *= invwin; ay *= invwin; az *= invwin; aw *= invwin;
        }
        int base = k * LDSP + c0;
        lds_out[base + 0] = ax;
        lds_out[base + 1] = ay;
        lds_out[base + 2] = az;
        lds_out[base + 3] = aw;
    }
    __syncthreads();
    float* outr = out + (size_t)r * (C_ * PHW_);
    for (int i = threadIdx.x; i < C_ * PHW_; i += 512) {
        int c = i / PHW_;
        int k = i - c * PHW_;
        outr[i] = lds_out[k * LDSP + c];
    }
}

// ---------------- fallback: original (B,C,H,W) layout, no workspace ----------------
__global__ __launch_bounds__(256) void prroi_pool_direct(const float* __restrict__ f,
                                                         const float* __restrict__ rois,
                                                         float* __restrict__ out) {
    int bin = blockIdx.x;
    int r  = bin / 49;
    int k  = bin - r * 49;
    int ph = k / 7;
    int pw = k - ph * 7;
    int c = threadIdx.x;

    int bb, h0, w0, npy, npx;
    float wy[7], wx[7], invwin;
    bool ok = bin_geom(rois, r, ph, pw, bb, h0, w0, npy, npx, wy, wx, invwin);

    size_t oidx = ((size_t)r * C_ + c) * PHW_ + k;
    if (!ok) { out[oidx] = 0.0f; return; }

    const float* fb = f + ((size_t)bb * C_ + c) * (H_ * W_);
    float acc = 0.0f;
#pragma unroll
    for (int dy = 0; dy < 7; ++dy) {
        int hh = h0 + dy;
        if (dy >= npy || hh < 0 || hh >= H_) continue;
        float row = 0.0f;
#pragma unroll
        for (int dx = 0; dx < 7; ++dx) {
            int wwp = w0 + dx;
            if (dx >= npx || wwp < 0 || wwp >= W_) continue;
            row = fmaf(wx[dx], fb[hh * W_ + wwp], row);
        }
        acc = fmaf(wy[dy], row, acc);
    }
    out[oidx] = acc * invwin;
}

extern "C" void kernel_launch(void* const* d_in, const int* in_sizes, int n_in,
                              void* d_out, int out_size, void* d_ws, size_t ws_size,
                              hipStream_t stream) {
    const float* feat = (const float*)d_in[0];
    const float* rois = (const float*)d_in[1];
    float* out = (float*)d_out;

    const size_t feat_bytes = (size_t)B_ * C_ * H_ * W_ * sizeof(float);
    const size_t perm_bytes = (size_t)R_ * sizeof(int);

    if (ws_size >= feat_bytes + perm_bytes) {
        float* fT   = (float*)d_ws;
        int*   perm = (int*)((char*)d_ws + feat_bytes);
        dim3 tb(32, 8, 1);
        dim3 tg((H_ * W_) / 32, C_ / 32, B_);
        transpose_bchw_bhwc<<<tg, tb, 0, stream>>>(feat, fT);
        make_perm<<<1, 64, 0, stream>>>(rois, perm);
        prroi_pool_roi<<<R_, 512, 0, stream>>>(fT, rois, perm, out);
    } else {
        prroi_pool_direct<<<R_ * PHW_, 256, 0, stream>>>(feat, rois, out);
    }
}

// Round 4
// 97.156 us; speedup vs baseline: 1.8726x; 1.2501x over previous
//
#include <hip/hip_runtime.h>
#include <hip/hip_fp16.h>

#define R_   1024
#define B_   4
#define C_   256
#define H_   64
#define W_   64
#define PHW_ 49
#define GREC 16    // 16 f32 dwords per bin geometry record (64 B)
#define LROW 260   // ushort columns per LDS row (520 B, 8B-aligned rows)

__device__ __forceinline__ void cell_w(float start, float end, float s, float& g0, float& g1) {
    float y0 = fmaxf(start, s);
    float yl = fmaxf(fminf(end, s + 1.0f), y0);
    float a  = y0 - s;
    float la = yl - s;
    g0 = la - 0.5f * la * la - a + 0.5f * a * a;
    g1 = 0.5f * la * la - 0.5f * a * a;
}

// ---------------- transpose (B,C,H,W) -> (B,H*W,C) ----------------
__global__ __launch_bounds__(256) void transpose_bchw_bhwc(const float* __restrict__ in,
                                                           float* __restrict__ out) {
    __shared__ float tile[32][33];
    int b  = blockIdx.z;
    int c0 = blockIdx.y * 32;
    int p0 = blockIdx.x * 32;
    int tx = threadIdx.x;
    int ty = threadIdx.y;
    const float* src = in + (size_t)b * C_ * (H_ * W_);
#pragma unroll
    for (int i = 0; i < 32; i += 8)
        tile[ty + i][tx] = src[(size_t)(c0 + ty + i) * (H_ * W_) + (p0 + tx)];
    __syncthreads();
    float* dst = out + (size_t)b * (H_ * W_) * C_;
#pragma unroll
    for (int i = 0; i < 32; i += 8)
        dst[(size_t)(p0 + ty + i) * C_ + (c0 + tx)] = tile[tx][ty + i];
}

// ------- fused: deterministic ROI bucket-sort (block 196) + per-bin geometry (blocks 0..195) -------
__global__ __launch_bounds__(256) void make_perm_geom(const float* __restrict__ rois,
                                                      int* __restrict__ perm,
                                                      float* __restrict__ geom) {
    if (blockIdx.x == 196) {
        // 1 wave, ballot-based stable counting sort by (batch, y-band). Deterministic.
        if (threadIdx.x >= 64) return;
        int lane = threadIdx.x;
        unsigned long long below = (1ull << lane) - 1ull;
        int key[16];
#pragma unroll
        for (int i = 0; i < 16; ++i) {
            int idx = i * 64 + lane;
            const float* roi = rois + idx * 5;
            int b = (int)roi[0];
            float yc = (roi[2] + roi[4]) * 0.5f * 0.0625f;
            int yb = min(3, max(0, (int)(yc * 0.0625f)));
            key[i] = b * 4 + yb;
        }
        int cnt[16];
#pragma unroll
        for (int k = 0; k < 16; ++k) cnt[k] = 0;
        for (int i = 0; i < 16; ++i)
#pragma unroll
            for (int k = 0; k < 16; ++k)
                cnt[k] += __popcll(__ballot(key[i] == k));
        int off[16]; int acc = 0;
#pragma unroll
        for (int k = 0; k < 16; ++k) { off[k] = acc; acc += cnt[k]; }
        for (int i = 0; i < 16; ++i) {
#pragma unroll
            for (int k = 0; k < 16; ++k) {
                unsigned long long m = __ballot(key[i] == k);
                if (key[i] == k)
                    perm[off[k] + __popcll(m & below)] = i * 64 + lane;
                off[k] += __popcll(m);
            }
        }
        return;
    }

    int i = blockIdx.x * 256 + threadIdx.x;
    if (i >= R_ * PHW_) return;
    int r  = i / PHW_;
    int k  = i - r * PHW_;
    int ph = k / 7, pw = k - ph * 7;
    const float* roi = rois + r * 5;
    int bb = (int)roi[0];
    float x1 = roi[1] * 0.0625f, y1 = roi[2] * 0.0625f;
    float x2 = roi[3] * 0.0625f, y2 = roi[4] * 0.0625f;
    float rw = fmaxf(x2 - x1, 0.0f), rh = fmaxf(y2 - y1, 0.0f);
    float bw = rw / 7.0f, bh = rh / 7.0f;
    float win = bw * bh;

    float rec[GREC];
#pragma unroll
    for (int t = 0; t < GREC; ++t) rec[t] = 0.0f;

    if (win > 0.0f) {
        float ws = x1 + bw * (float)pw, we = ws + bw;
        float hs = y1 + bh * (float)ph, he = hs + bh;
        float s0w = floorf(ws), s0h = floorf(hs);
        int w0 = (int)s0w, h0 = (int)s0h;   // always >= 0 for this input range
        float wy[7], wx[7];
#pragma unroll
        for (int t = 0; t < 7; ++t) { wy[t] = 0.0f; wx[t] = 0.0f; }
#pragma unroll
        for (int o = 0; o < 6; ++o) {
            float g0, g1;
            cell_w(hs, he, s0h + (float)o, g0, g1);
            wy[o] += g0; wy[o + 1] += g1;
            cell_w(ws, we, s0w + (float)o, g0, g1);
            wx[o] += g0; wx[o + 1] += g1;
        }
        int npy = min(7, max(0, (int)ceilf(he - s0h + 1.0f)));
        int npx = min(7, max(0, (int)ceilf(we - s0w + 1.0f)));
        npy = max(0, min(npy, H_ - h0));    // fold boundary clip into count
        npx = max(0, min(npx, W_ - w0));
        float invwin = 1.0f / win;
#pragma unroll
        for (int t = 0; t < 7; ++t) { rec[t] = wy[t] * invwin; rec[7 + t] = wx[t]; }
        rec[14] = __int_as_float(h0 | (w0 << 8) | (npy << 16) | (npx << 24));
    }
    rec[15] = __int_as_float(bb);

    float4* gp = (float4*)(geom + (size_t)i * GREC);
    gp[0] = make_float4(rec[0],  rec[1],  rec[2],  rec[3]);
    gp[1] = make_float4(rec[4],  rec[5],  rec[6],  rec[7]);
    gp[2] = make_float4(rec[8],  rec[9],  rec[10], rec[11]);
    gp[3] = make_float4(rec[12], rec[13], rec[14], rec[15]);
}

// ---------------- main: one block per ROI, f16 LDS staging, coalesced flush ----------------
__global__ __launch_bounds__(512, 8) void prroi_pool_roi(const float* __restrict__ fT,
                                                         const int* __restrict__ perm,
                                                         const float* __restrict__ geom,
                                                         float* __restrict__ out) {
    __shared__ __align__(16) unsigned short lds_h[PHW_ * LROW];   // 25,480 B
    int bid  = blockIdx.x;
    int spos = ((bid & 7) << 7) | (bid >> 3);   // XCD x owns sorted chunk [x*128,(x+1)*128)
    int r    = __builtin_amdgcn_readfirstlane(perm[spos]);
    int wid  = threadIdx.x >> 6;
    int lane = threadIdx.x & 63;
    int c0   = lane * 4;

    const float* grec0 = geom + (size_t)r * PHW_ * GREC;   // uniform base -> s_loads
    int bb = __float_as_int(grec0[15]);
    const float* fb = fT + (size_t)bb * (H_ * W_ * C_) + c0;

    for (int k = wid; k < PHW_; k += 8) {
        const float* g = grec0 + k * GREC;
        float4 q0 = *(const float4*)(g);
        float4 q1 = *(const float4*)(g + 4);
        float4 q2 = *(const float4*)(g + 8);
        float4 q3 = *(const float4*)(g + 12);
        float wy[7] = {q0.x, q0.y, q0.z, q0.w, q1.x, q1.y, q1.z};
        float wx[7] = {q1.w, q2.x, q2.y, q2.z, q2.w, q3.x, q3.y};
        int pk  = __float_as_int(q3.z);
        int h0  = pk & 0xff;
        int w0  = (pk >> 8)  & 0xff;
        int npy = (pk >> 16) & 0xff;
        int npx = (pk >> 24) & 0xff;

        const float* fr = fb + (h0 * W_ + w0) * C_;
        float ax = 0.0f, ay = 0.0f, az = 0.0f, aw = 0.0f;
#pragma unroll
        for (int dy = 0; dy < 7; ++dy) {
            if (dy < npy) {                       // wave-uniform
                const float* rp = fr + dy * (W_ * C_);
                float rx = 0.0f, ry = 0.0f, rz = 0.0f, rw = 0.0f;
#pragma unroll
                for (int dx = 0; dx < 7; ++dx) {
                    if (dx < npx) {               // wave-uniform
                        float4 v = *(const float4*)(rp + dx * C_);
                        float gx = wx[dx];
                        rx = fmaf(gx, v.x, rx);
                        ry = fmaf(gx, v.y, ry);
                        rz = fmaf(gx, v.z, rz);
                        rw = fmaf(gx, v.w, rw);
                    }
                }
                float gy = wy[dy];
                ax = fmaf(gy, rx, ax);
                ay = fmaf(gy, ry, ay);
                az = fmaf(gy, rz, az);
                aw = fmaf(gy, rw, aw);
            }
        }
        __half2 lo = __floats2half2_rn(ax, ay);
        __half2 hi = __floats2half2_rn(az, aw);
        __half2* dst = (__half2*)&lds_h[k * LROW + c0];   // 8B-aligned, contiguous per wave
        dst[0] = lo;
        dst[1] = hi;
    }
    __syncthreads();

    float* outr = out + (size_t)r * (C_ * PHW_);
    const __half* lh = (const __half*)lds_h;
#pragma unroll 4
    for (int j = threadIdx.x; j < C_ * PHW_; j += 512) {
        int c = j / PHW_;           // const-div -> magic mul
        int k = j - c * PHW_;
        outr[j] = __half2float(lh[k * LROW + c]);   // fully contiguous 50KB store per block
    }
}

// ---------------- fallback: original (B,C,H,W) layout, no workspace ----------------
__global__ __launch_bounds__(256) void prroi_pool_direct(const float* __restrict__ f,
                                                         const float* __restrict__ rois,
                                                         float* __restrict__ out) {
    int bin = blockIdx.x;
    int r  = bin / PHW_;
    int k  = bin - r * PHW_;
    int ph = k / 7;
    int pw = k - ph * 7;
    int c = threadIdx.x;

    const float* roi = rois + r * 5;
    int bb = (int)roi[0];
    float x1 = roi[1] * 0.0625f, y1 = roi[2] * 0.0625f;
    float x2 = roi[3] * 0.0625f, y2 = roi[4] * 0.0625f;
    float rw = fmaxf(x2 - x1, 0.0f), rh = fmaxf(y2 - y1, 0.0f);
    float bw = rw / 7.0f, bh = rh / 7.0f;
    float win = bw * bh;
    size_t oidx = ((size_t)r * C_ + c) * PHW_ + k;
    if (!(win > 0.0f)) { out[oidx] = 0.0f; return; }

    float ws = x1 + bw * (float)pw, we = ws + bw;
    float hs = y1 + bh * (float)ph, he = hs + bh;
    float s0w = floorf(ws), s0h = floorf(hs);
    int w0 = (int)s0w, h0 = (int)s0h;
    float wy[7], wx[7];
#pragma unroll
    for (int t = 0; t < 7; ++t) { wy[t] = 0.0f; wx[t] = 0.0f; }
#pragma unroll
    for (int o = 0; o < 6; ++o) {
        float g0, g1;
        cell_w(hs, he, s0h + (float)o, g0, g1);
        wy[o] += g0; wy[o + 1] += g1;
        cell_w(ws, we, s0w + (float)o, g0, g1);
        wx[o] += g0; wx[o + 1] += g1;
    }
    int npy = min(7, max(0, (int)ceilf(he - s0h + 1.0f)));
    int npx = min(7, max(0, (int)ceilf(we - s0w + 1.0f)));
    npy = max(0, min(npy, H_ - h0));
    npx = max(0, min(npx, W_ - w0));

    const float* fbc = f + ((size_t)bb * C_ + c) * (H_ * W_);
    float acc = 0.0f;
#pragma unroll
    for (int dy = 0; dy < 7; ++dy) {
        if (dy < npy) {
            float row = 0.0f;
#pragma unroll
            for (int dx = 0; dx < 7; ++dx) {
                if (dx < npx)
                    row = fmaf(wx[dx], fbc[(h0 + dy) * W_ + (w0 + dx)], row);
            }
            acc = fmaf(wy[dy], row, acc);
        }
    }
    out[oidx] = acc / win;
}

extern "C" void kernel_launch(void* const* d_in, const int* in_sizes, int n_in,
                              void* d_out, int out_size, void* d_ws, size_t ws_size,
                              hipStream_t stream) {
    const float* feat = (const float*)d_in[0];
    const float* rois = (const float*)d_in[1];
    float* out = (float*)d_out;

    const size_t feat_bytes = (size_t)B_ * C_ * H_ * W_ * sizeof(float);       // 16,777,216
    const size_t perm_bytes = (size_t)R_ * sizeof(int);                        // 4,096
    const size_t geom_bytes = (size_t)R_ * PHW_ * GREC * sizeof(float);        // 3,211,264

    if (ws_size >= feat_bytes + perm_bytes + geom_bytes) {
        float* fT   = (float*)d_ws;
        int*   perm = (int*)((char*)d_ws + feat_bytes);
        float* geom = (float*)((char*)d_ws + feat_bytes + perm_bytes);
        dim3 tb(32, 8, 1);
        dim3 tg((H_ * W_) / 32, C_ / 32, B_);
        transpose_bchw_bhwc<<<tg, tb, 0, stream>>>(feat, fT);
        make_perm_geom<<<197, 256, 0, stream>>>(rois, perm, geom);
        prroi_pool_roi<<<R_, 512, 0, stream>>>(fT, perm, geom, out);
    } else {
        prroi_pool_direct<<<R_ * PHW_, 256, 0, stream>>>(feat, rois, out);
    }
}